// Round 15
// baseline (54.429 us; speedup 1.0000x reference)
//
#include <hip/hip_runtime.h>

// Problem constants (hardcoded in the reference)
#define NPIX 65536   // 256*256 = 2^16
#define KK   361     // 19*19
#define LSZ  19
#define HWD  256
#define QB   16      // q-rows per sub-tile
#define CT   4       // sub-tiles per chunk
#define CHUNK 64     // q per block
#define GPART (NPIX / CHUNK)      // 1024 blocks
#define NTHR 384
#define NSLOT 8      // partial slots per row (window <= 7, one 64B line)
#define NS2  16      // s-strips for S1
#define SPS2 23      // s-rows per strip (last: 361 - 15*23 = 16)
#define DTC  82      // in2 LDS tile cols = CHUNK-1 + LSZ
#define PSL  92      // partial slots per subtile row (exactly 91 used)

// reflect-pad index (pad=9, size 256, mode="reflect"); arg is (coord + offset)
__device__ __forceinline__ int refl(int v) {
    v -= 9;
    v = v < 0 ? -v : v;
    v = v > 255 ? 510 - v : v;
    return v;
}

// ---------------------------------------------------------------------------
// S1a: partial column sums, contiguous float4 reads (the only cold HBM pass).
// ---------------------------------------------------------------------------
__global__ __launch_bounds__(256) void k_s1a(const float4* __restrict__ ker4,
                                             float4* __restrict__ part4) {
    const int p4 = blockIdx.x * 256 + threadIdx.x;   // [0, 16384)
    const int strip = blockIdx.y;
    const int s0 = strip * SPS2;
    const int n = (strip == NS2 - 1) ? (KK - s0) : SPS2;
    const float4* kp = ker4 + (size_t)s0 * (NPIX / 4) + p4;
    float4 acc = {0.f, 0.f, 0.f, 0.f};
#pragma unroll 8
    for (int s = 0; s < n; ++s) {
        float4 v = kp[(size_t)s * (NPIX / 4)];
        acc.x += v.x; acc.y += v.y; acc.z += v.z; acc.w += v.w;
    }
    part4[(size_t)strip * (NPIX / 4) + p4] = acc;
}

// S1b: rcpS1[p] = 1 / sum_strips
__global__ __launch_bounds__(256) void k_s1b(const float4* __restrict__ part4,
                                             float4* __restrict__ rcp4) {
    const int i = blockIdx.x * 256 + threadIdx.x;    // [0, 16384)
    float4 a = {0.f, 0.f, 0.f, 0.f};
#pragma unroll
    for (int s = 0; s < NS2; ++s) {
        float4 v = part4[(size_t)s * (NPIX / 4) + i];
        a.x += v.x; a.y += v.y; a.z += v.z; a.w += v.w;
    }
    rcp4[i] = float4{1.0f / a.x, 1.0f / a.y, 1.0f / a.z, 1.0f / a.w};
}

// ---------------------------------------------------------------------------
// k_part: R14 structure (stagger + XCD swizzle + chunk-carry), with the
// rowsum phase FUSED into staging:
//   - each staged float4 (4 consecutive elems) lies in <=2 subtile rows;
//     its per-row partial sums are computed in registers (free VALU under
//     the VMEM-bound stage) and written to part[16][92] at deterministic
//     slots (slot = G - (361r>>2); exactly 91 slots/row, all written).
//   - reducer: 4 waves, 16-lane groups: 6 strided reads + 4 shuffles per
//     row -> rcpS2s. 40 wave-DS-instrs vs 192 for the old per-row butterfly.
// ---------------------------------------------------------------------------
__global__ __launch_bounds__(NTHR) void k_part(const float* __restrict__ ker,
                                               const float* __restrict__ rcpS1,
                                               const float* __restrict__ in2,
                                               float2* __restrict__ partial) {
    // generation stagger (no effect on results, only phase timing)
    switch (blockIdx.x >> 8) {
        case 1: __builtin_amdgcn_s_sleep(10); break;
        case 2: __builtin_amdgcn_s_sleep(20); break;
        case 3: __builtin_amdgcn_s_sleep(30); break;
        default: break;
    }

    __shared__ float tile[QB * KK];      // 23,104 B
    __shared__ float dt[LSZ * DTC];      // 6,232 B
    __shared__ float part[QB][PSL];      // 5,888 B
    __shared__ float rcpS2s[QB];
    const int tid = threadIdx.x;
    const int lb  = ((blockIdx.x & 7) << 7) | (blockIdx.x >> 3);  // 1024 = 8*128
    const int q0  = lb * CHUNK;

    // stage reflected in2 patch (consumed after the k=0 stage barrier)
    {
        const int y0 = q0 >> 8, x0 = q0 & 255;
        for (int i = tid; i < LSZ * DTC; i += NTHR) {
            int ai = i / DTC, ci = i - ai * DTC;
            dt[i] = in2[refl(y0 + ai) * HWD + refl(x0 + ci)];
        }
    }

    // per-lane chunk-carry state
    const int t  = tid;
    const int j0 = t * NPIX + q0;             // < 2^25
    const int r0 = j0 / KK;
    const int jm = j0 - r0 * KK;
    const int d0 = (jm == 0) ? CHUNK : (KK - jm);
    const int split = d0 < CHUNK ? d0 : CHUNK;     // [1, 64]
    const int la = t / LSZ, lb2 = t - LSZ * la;
    const int dbase = la * DTC + lb2;
    float ad = 0.f, as = 0.f, sd = 0.f, ss = 0.f;

    for (int k = 0; k < CT; ++k) {
        __syncthreads();   // previous sub-tile fully consumed (and dt, k=0)
        // stage ker sub-tile k (coalesced float4), scaled by rcpS1;
        // row partials computed in-flight.
        const int basek = (q0 + k * QB) * KK;            // %4 == 0
        const float4* k4 = (const float4*)(ker + basek);
        for (int i = tid; i < (QB * KK) / 4; i += NTHR) {
            float4 v = k4[i];
            int m = basek + i * 4;
            const float4 s = *(const float4*)(rcpS1 + (m & (NPIX - 1)));
            v.x *= s.x; v.y *= s.y; v.z *= s.z; v.w *= s.w;
            *(float4*)(tile + i * 4) = v;
            // per-row partials: elems 4i..4i+3 lie in rows lo (c elems) and
            // lo+1 (4-c elems, only when c<4).
            const int e0 = i * 4;                 // [0, 5776)
            const int lo = e0 / KK;               // local row
            const int p0 = e0 - lo * KK;
            int c = KK - p0; c = c < 4 ? c : 4;
            float pa = v.x;
            if (c > 1) pa += v.y;
            if (c > 2) pa += v.z;
            if (c > 3) pa += v.w;
            part[lo][i - ((lo * KK) >> 2)] = pa;  // slot = G - first(lo)
            if (c < 4) {
                float pb = v.w;
                if (c < 3) pb += v.z;
                if (c < 2) pb += v.y;
                part[lo + 1][0] = pb;             // boundary group is slot 0
            }
        }
        __syncthreads();
        // reduce 16 rows x 91 slots: waves 0..3, one 16-lane group per row
        if (tid < 256) {
            const int r   = tid >> 4;             // 0..15
            const int s16 = tid & 15;
            float acc = 0.f;
            for (int s = s16; s < 91; s += 16) acc += part[r][s];
            acc += __shfl_xor(acc, 1);
            acc += __shfl_xor(acc, 2);
            acc += __shfl_xor(acc, 4);
            acc += __shfl_xor(acc, 8);
            if (s16 == 0) rcpS2s[r] = 1.0f / acc;
        }
        __syncthreads();
        // accum (chunk-carry + snapshot), unchanged
        if (t < KK) {
#pragma unroll
            for (int o = 0; o < QB; ++o) {
                const int off = k * QB + o;
                if (off == split) { sd = ad; ss = as; }  // snapshot at boundary
                float v = tile[o * KK + t] * rcpS2s[o];
                float d = dt[dbase + off];
                ad += d * v;
                as += v;
            }
        }
    }

    if (t < KK) {
        const int slot = lb & (NSLOT - 1);
        if (split == CHUNK) {
            partial[(size_t)r0 * NSLOT + slot] = float2{ad, as};
        } else {
            partial[(size_t)r0 * NSLOT + slot] = float2{sd, ss};
            partial[(size_t)(r0 + 1) * NSLOT + slot] = float2{ad - sd, as - ss};
        }
    }
}

// ---------------------------------------------------------------------------
// k_out2: sum the valid slot window for row r (no zero-init needed).
// Chunks touching row r: [qs>>6 .. ql>>6] (mod GPART), <= 7 wide;
// slots = chunk & 7, distinct. Whole window lives in ONE 64B line.
// ---------------------------------------------------------------------------
__global__ __launch_bounds__(256) void k_out2(const float2* __restrict__ partial,
                                              float* __restrict__ out) {
    const int r = blockIdx.x * 256 + threadIdx.x;
    const int j0 = r * KK;
    const int qs = j0 & (NPIX - 1);
    const int ql = (j0 + KK - 1) & (NPIX - 1);
    const int first = qs >> 6;
    const int last  = ql >> 6;
    const int cnt = ((last - first) & (GPART - 1)) + 1;
    const float2* p = partial + (size_t)r * NSLOT;
    float dot = 0.f, sum = 0.f;
    for (int i = 0; i < cnt; ++i) {
        float2 v = p[(first + i) & (NSLOT - 1)];
        dot += v.x; sum += v.y;
    }
    out[r] = dot / sum;
}

// ---------------------------------------------------------------------------
// Minimal fallback path (tiny ws): direct strided gathers.
// ---------------------------------------------------------------------------
__global__ __launch_bounds__(256) void k_s1(const float* __restrict__ ker,
                                            float* __restrict__ rcpS1) {
    int p = blockIdx.x * blockDim.x + threadIdx.x;
    const float* kp = ker + p;
    float a = 0.f;
    for (int s = 0; s < KK; ++s) a += kp[(size_t)s * NPIX];
    rcpS1[p] = 1.0f / a;
}

__global__ __launch_bounds__(256) void k_s2_fallback(const float* __restrict__ ker,
                                                     const float* __restrict__ rcpS1,
                                                     float* __restrict__ rcpS2) {
    int lane = threadIdx.x & 63;
    int q = blockIdx.x * 4 + (threadIdx.x >> 6);
    int base = q * KK;
    float acc = 0.f;
    for (int t = lane; t < KK; t += 64)
        acc += ker[base + t] * rcpS1[(base + t) & (NPIX - 1)];
    for (int m = 1; m < 64; m <<= 1) acc += __shfl_xor(acc, m);
    if (lane == 0) rcpS2[q] = 1.0f / acc;
}

__global__ __launch_bounds__(256) void k_out_fallback(const float* __restrict__ ker,
                                                      const float* __restrict__ rcpS1,
                                                      const float* __restrict__ rcpS2,
                                                      const float* __restrict__ in2,
                                                      float* __restrict__ out) {
    int lane = threadIdx.x & 63;
    int r = blockIdx.x * 4 + (threadIdx.x >> 6);
    float vsum = 0.f, vdot = 0.f;
    for (int u = lane; u < KK; u += 64) {
        int jj = r * KK + u;
        int t  = jj >> 16;
        int q  = jj & (NPIX - 1);
        int m  = q * KK + t;
        float v = ker[m] * rcpS1[m & (NPIX - 1)] * rcpS2[q];
        int y = q >> 8, x = q & 255;
        int a = t / LSZ, b = t - a * LSZ;
        float d = in2[refl(y + a) * HWD + refl(x + b)];
        vsum += v;
        vdot += d * v;
    }
    for (int mm = 1; mm < 64; mm <<= 1) {
        vsum += __shfl_xor(vsum, mm);
        vdot += __shfl_xor(vdot, mm);
    }
    if (lane == 0) out[r] = vdot / vsum;
}

extern "C" void kernel_launch(void* const* d_in, const int* in_sizes, int n_in,
                              void* d_out, int out_size, void* d_ws, size_t ws_size,
                              hipStream_t stream) {
    const float* inp = (const float*)d_in[0];   // (1,3,256,256)
    const float* ker = (const float*)d_in[1];   // (19,19,256,256)
    float* out = (float*)d_out;                 // (1,1,256,256)
    const float* in2 = inp + 2 * NPIX;          // channel 2

    float*  rcpS1   = (float*)d_ws;                           // NPIX
    float*  s1part  = rcpS1 + NPIX;                           // NS2*NPIX
    float2* partial = (float2*)(s1part + (size_t)NS2 * NPIX); // NPIX*NSLOT float2

    const size_t needed = ((size_t)NPIX * (1 + NS2) +
                           (size_t)NPIX * NSLOT * 2) * sizeof(float);  // ~8.25 MB

    if (ws_size >= needed) {
        dim3 g1(NPIX / 4 / 256, NS2);   // (64, 16)
        k_s1a<<<g1, 256, 0, stream>>>((const float4*)ker, (float4*)s1part);
        k_s1b<<<NPIX / 4 / 256, 256, 0, stream>>>((const float4*)s1part, (float4*)rcpS1);
        k_part<<<GPART, NTHR, 0, stream>>>(ker, rcpS1, in2, partial);
        k_out2<<<NPIX / 256, 256, 0, stream>>>(partial, out);
    } else {
        float* rcpS2 = rcpS1 + NPIX;   // fallback needs only 512 KB
        k_s1<<<NPIX / 256, 256, 0, stream>>>(ker, rcpS1);
        k_s2_fallback<<<NPIX / 4, 256, 0, stream>>>(ker, rcpS1, rcpS2);
        k_out_fallback<<<NPIX / 4, 256, 0, stream>>>(ker, rcpS1, rcpS2, in2, out);
    }
}

// Round 16
// 53.446 us; speedup vs baseline: 1.0184x; 1.0184x over previous
//
#include <hip/hip_runtime.h>

// Problem constants (hardcoded in the reference)
#define NPIX 65536   // 256*256 = 2^16
#define KK   361     // 19*19
#define LSZ  19
#define HWD  256
#define QB   16      // q-rows per sub-tile
#define CT   4       // sub-tiles per chunk
#define CHUNK 64     // q per block
#define GPART (NPIX / CHUNK)      // 1024 blocks
#define NTHR 384
#define NSLOT 8      // partial slots per row (window <= 7, one 64B line)
#define NS2  16      // s-strips for S1
#define SPS2 23      // s-rows per strip (last: 361 - 15*23 = 16)
#define DTC  82      // in2 LDS tile cols = CHUNK-1 + LSZ

// reflect-pad index (pad=9, size 256, mode="reflect"); arg is (coord + offset)
__device__ __forceinline__ int refl(int v) {
    v -= 9;
    v = v < 0 ? -v : v;
    v = v > 255 ? 510 - v : v;
    return v;
}

// ---------------------------------------------------------------------------
// S1a: partial column sums, contiguous float4 reads (the only cold HBM pass).
// ---------------------------------------------------------------------------
__global__ __launch_bounds__(256) void k_s1a(const float4* __restrict__ ker4,
                                             float4* __restrict__ part4) {
    const int p4 = blockIdx.x * 256 + threadIdx.x;   // [0, 16384)
    const int strip = blockIdx.y;
    const int s0 = strip * SPS2;
    const int n = (strip == NS2 - 1) ? (KK - s0) : SPS2;
    const float4* kp = ker4 + (size_t)s0 * (NPIX / 4) + p4;
    float4 acc = {0.f, 0.f, 0.f, 0.f};
#pragma unroll 8
    for (int s = 0; s < n; ++s) {
        float4 v = kp[(size_t)s * (NPIX / 4)];
        acc.x += v.x; acc.y += v.y; acc.z += v.z; acc.w += v.w;
    }
    part4[(size_t)strip * (NPIX / 4) + p4] = acc;
}

// S1b: rcpS1[p] = 1 / sum_strips
__global__ __launch_bounds__(256) void k_s1b(const float4* __restrict__ part4,
                                             float4* __restrict__ rcp4) {
    const int i = blockIdx.x * 256 + threadIdx.x;    // [0, 16384)
    float4 a = {0.f, 0.f, 0.f, 0.f};
#pragma unroll
    for (int s = 0; s < NS2; ++s) {
        float4 v = part4[(size_t)s * (NPIX / 4) + i];
        a.x += v.x; a.y += v.y; a.z += v.z; a.w += v.w;
    }
    rcp4[i] = float4{1.0f / a.x, 1.0f / a.y, 1.0f / a.z, 1.0f / a.w};
}

// ---------------------------------------------------------------------------
// k_part: R14 structure (stagger + XCD swizzle + chunk-carry + snapshot),
// with ONE change: the per-row sums read ker from GLOBAL (L2-hot — the stage
// phase just pulled these exact lines; 92 KB x 32 CUs = 2.9 MB <= 4 MB/XCD
// L2) instead of from LDS. Same products ker*rcpS1, same stride-64 order,
// same butterfly -> bit-identical; removes ~6 b32 LDS reads/row from the DS
// pipe, putting the CU's DS demand below the L3 feed rate.
// (R11/R13 read rowsum from L3-COLD global and lost; this is the L2-hot cell.)
// ---------------------------------------------------------------------------
__global__ __launch_bounds__(NTHR) void k_part(const float* __restrict__ ker,
                                               const float* __restrict__ rcpS1,
                                               const float* __restrict__ in2,
                                               float2* __restrict__ partial) {
    // generation stagger (no effect on results, only phase timing)
    switch (blockIdx.x >> 8) {
        case 1: __builtin_amdgcn_s_sleep(10); break;
        case 2: __builtin_amdgcn_s_sleep(20); break;
        case 3: __builtin_amdgcn_s_sleep(30); break;
        default: break;
    }

    __shared__ float tile[QB * KK];      // 23,104 B
    __shared__ float dt[LSZ * DTC];      // 6,232 B
    __shared__ float rcpS2s[QB];
    const int tid = threadIdx.x;
    const int lb  = ((blockIdx.x & 7) << 7) | (blockIdx.x >> 3);  // 1024 = 8*128
    const int q0  = lb * CHUNK;

    // stage reflected in2 patch (consumed after the k=0 stage barrier)
    {
        const int y0 = q0 >> 8, x0 = q0 & 255;
        for (int i = tid; i < LSZ * DTC; i += NTHR) {
            int ai = i / DTC, ci = i - ai * DTC;
            dt[i] = in2[refl(y0 + ai) * HWD + refl(x0 + ci)];
        }
    }

    // per-lane chunk-carry state
    const int t  = tid;
    const int j0 = t * NPIX + q0;             // < 2^25
    const int r0 = j0 / KK;
    const int jm = j0 - r0 * KK;
    const int d0 = (jm == 0) ? CHUNK : (KK - jm);
    const int split = d0 < CHUNK ? d0 : CHUNK;     // [1, 64]
    const int la = t / LSZ, lb2 = t - LSZ * la;
    const int dbase = la * DTC + lb2;
    float ad = 0.f, as = 0.f, sd = 0.f, ss = 0.f;
    const int wave = tid >> 6, lane = tid & 63;

    for (int k = 0; k < CT; ++k) {
        __syncthreads();   // previous sub-tile fully consumed (and dt, k=0)
        // stage ker sub-tile k (coalesced float4), scaled by rcpS1
        const int basek = (q0 + k * QB) * KK;            // %4 == 0
        const float4* k4 = (const float4*)(ker + basek);
        for (int i = tid; i < (QB * KK) / 4; i += NTHR) {
            float4 v = k4[i];
            int m = basek + i * 4;
            const float4 s = *(const float4*)(rcpS1 + (m & (NPIX - 1)));
            v.x *= s.x; v.y *= s.y; v.z *= s.z; v.w *= s.w;
            *(float4*)(tile + i * 4) = v;
        }
        __syncthreads();
        // per-q row sums from GLOBAL (L2-hot: stage just streamed these
        // lines). Same products/order as the LDS version -> bit-identical.
        for (int qq = wave; qq < QB; qq += 6) {
            const int rb = (q0 + k * QB + qq) * KK;
            float acc = 0.f;
#pragma unroll
            for (int e = lane; e < KK; e += 64)
                acc += ker[rb + e] * rcpS1[(rb + e) & (NPIX - 1)];
            for (int m = 1; m < 64; m <<= 1) acc += __shfl_xor(acc, m);
            if (lane == 0) rcpS2s[qq] = 1.0f / acc;
        }
        __syncthreads();
        if (t < KK) {
#pragma unroll
            for (int o = 0; o < QB; ++o) {
                const int off = k * QB + o;
                if (off == split) { sd = ad; ss = as; }  // snapshot at boundary
                float v = tile[o * KK + t] * rcpS2s[o];
                float d = dt[dbase + off];
                ad += d * v;
                as += v;
            }
        }
    }

    if (t < KK) {
        const int slot = lb & (NSLOT - 1);
        if (split == CHUNK) {
            partial[(size_t)r0 * NSLOT + slot] = float2{ad, as};
        } else {
            partial[(size_t)r0 * NSLOT + slot] = float2{sd, ss};
            partial[(size_t)(r0 + 1) * NSLOT + slot] = float2{ad - sd, as - ss};
        }
    }
}

// ---------------------------------------------------------------------------
// k_out2: sum the valid slot window for row r (no zero-init needed).
// Chunks touching row r: [qs>>6 .. ql>>6] (mod GPART), <= 7 wide;
// slots = chunk & 7, distinct. Whole window lives in ONE 64B line.
// ---------------------------------------------------------------------------
__global__ __launch_bounds__(256) void k_out2(const float2* __restrict__ partial,
                                              float* __restrict__ out) {
    const int r = blockIdx.x * 256 + threadIdx.x;
    const int j0 = r * KK;
    const int qs = j0 & (NPIX - 1);
    const int ql = (j0 + KK - 1) & (NPIX - 1);
    const int first = qs >> 6;
    const int last  = ql >> 6;
    const int cnt = ((last - first) & (GPART - 1)) + 1;
    const float2* p = partial + (size_t)r * NSLOT;
    float dot = 0.f, sum = 0.f;
    for (int i = 0; i < cnt; ++i) {
        float2 v = p[(first + i) & (NSLOT - 1)];
        dot += v.x; sum += v.y;
    }
    out[r] = dot / sum;
}

// ---------------------------------------------------------------------------
// Minimal fallback path (tiny ws): direct strided gathers.
// ---------------------------------------------------------------------------
__global__ __launch_bounds__(256) void k_s1(const float* __restrict__ ker,
                                            float* __restrict__ rcpS1) {
    int p = blockIdx.x * blockDim.x + threadIdx.x;
    const float* kp = ker + p;
    float a = 0.f;
    for (int s = 0; s < KK; ++s) a += kp[(size_t)s * NPIX];
    rcpS1[p] = 1.0f / a;
}

__global__ __launch_bounds__(256) void k_s2_fallback(const float* __restrict__ ker,
                                                     const float* __restrict__ rcpS1,
                                                     float* __restrict__ rcpS2) {
    int lane = threadIdx.x & 63;
    int q = blockIdx.x * 4 + (threadIdx.x >> 6);
    int base = q * KK;
    float acc = 0.f;
    for (int t = lane; t < KK; t += 64)
        acc += ker[base + t] * rcpS1[(base + t) & (NPIX - 1)];
    for (int m = 1; m < 64; m <<= 1) acc += __shfl_xor(acc, m);
    if (lane == 0) rcpS2[q] = 1.0f / acc;
}

__global__ __launch_bounds__(256) void k_out_fallback(const float* __restrict__ ker,
                                                      const float* __restrict__ rcpS1,
                                                      const float* __restrict__ rcpS2,
                                                      const float* __restrict__ in2,
                                                      float* __restrict__ out) {
    int lane = threadIdx.x & 63;
    int r = blockIdx.x * 4 + (threadIdx.x >> 6);
    float vsum = 0.f, vdot = 0.f;
    for (int u = lane; u < KK; u += 64) {
        int jj = r * KK + u;
        int t  = jj >> 16;
        int q  = jj & (NPIX - 1);
        int m  = q * KK + t;
        float v = ker[m] * rcpS1[m & (NPIX - 1)] * rcpS2[q];
        int y = q >> 8, x = q & 255;
        int a = t / LSZ, b = t - a * LSZ;
        float d = in2[refl(y + a) * HWD + refl(x + b)];
        vsum += v;
        vdot += d * v;
    }
    for (int mm = 1; mm < 64; mm <<= 1) {
        vsum += __shfl_xor(vsum, mm);
        vdot += __shfl_xor(vdot, mm);
    }
    if (lane == 0) out[r] = vdot / vsum;
}

extern "C" void kernel_launch(void* const* d_in, const int* in_sizes, int n_in,
                              void* d_out, int out_size, void* d_ws, size_t ws_size,
                              hipStream_t stream) {
    const float* inp = (const float*)d_in[0];   // (1,3,256,256)
    const float* ker = (const float*)d_in[1];   // (19,19,256,256)
    float* out = (float*)d_out;                 // (1,1,256,256)
    const float* in2 = inp + 2 * NPIX;          // channel 2

    float*  rcpS1   = (float*)d_ws;                           // NPIX
    float*  s1part  = rcpS1 + NPIX;                           // NS2*NPIX
    float2* partial = (float2*)(s1part + (size_t)NS2 * NPIX); // NPIX*NSLOT float2

    const size_t needed = ((size_t)NPIX * (1 + NS2) +
                           (size_t)NPIX * NSLOT * 2) * sizeof(float);  // ~8.25 MB

    if (ws_size >= needed) {
        dim3 g1(NPIX / 4 / 256, NS2);   // (64, 16)
        k_s1a<<<g1, 256, 0, stream>>>((const float4*)ker, (float4*)s1part);
        k_s1b<<<NPIX / 4 / 256, 256, 0, stream>>>((const float4*)s1part, (float4*)rcpS1);
        k_part<<<GPART, NTHR, 0, stream>>>(ker, rcpS1, in2, partial);
        k_out2<<<NPIX / 256, 256, 0, stream>>>(partial, out);
    } else {
        float* rcpS2 = rcpS1 + NPIX;   // fallback needs only 512 KB
        k_s1<<<NPIX / 256, 256, 0, stream>>>(ker, rcpS1);
        k_s2_fallback<<<NPIX / 4, 256, 0, stream>>>(ker, rcpS1, rcpS2);
        k_out_fallback<<<NPIX / 4, 256, 0, stream>>>(ker, rcpS1, rcpS2, in2, out);
    }
}

// Round 17
// 45.444 us; speedup vs baseline: 1.1977x; 1.1761x over previous
//
#include <hip/hip_runtime.h>

// Problem constants (hardcoded in the reference)
#define NPIX 65536   // 256*256 = 2^16
#define KK   361     // 19*19
#define LSZ  19
#define HWD  256
#define QB   16      // q-rows per sub-tile
#define CT   4       // sub-tiles per chunk
#define CHUNK 64     // q per block
#define GPART (NPIX / CHUNK)      // 1024 blocks
#define NTHR 512     // 8 waves: full 32-wave/CU occupancy at 4 blocks/CU
#define NSLOT 8      // partial slots per row (window <= 7, one 64B line)
#define NS2  16      // s-strips for S1
#define SPS2 23      // s-rows per strip (last: 361 - 15*23 = 16)
#define DTC  82      // in2 LDS tile cols = CHUNK-1 + LSZ

// reflect-pad index (pad=9, size 256, mode="reflect"); arg is (coord + offset)
__device__ __forceinline__ int refl(int v) {
    v -= 9;
    v = v < 0 ? -v : v;
    v = v > 255 ? 510 - v : v;
    return v;
}

// ---------------------------------------------------------------------------
// S1a: partial column sums, contiguous float4 reads (the only cold HBM pass).
// ---------------------------------------------------------------------------
__global__ __launch_bounds__(256) void k_s1a(const float4* __restrict__ ker4,
                                             float4* __restrict__ part4) {
    const int p4 = blockIdx.x * 256 + threadIdx.x;   // [0, 16384)
    const int strip = blockIdx.y;
    const int s0 = strip * SPS2;
    const int n = (strip == NS2 - 1) ? (KK - s0) : SPS2;
    const float4* kp = ker4 + (size_t)s0 * (NPIX / 4) + p4;
    float4 acc = {0.f, 0.f, 0.f, 0.f};
#pragma unroll 8
    for (int s = 0; s < n; ++s) {
        float4 v = kp[(size_t)s * (NPIX / 4)];
        acc.x += v.x; acc.y += v.y; acc.z += v.z; acc.w += v.w;
    }
    part4[(size_t)strip * (NPIX / 4) + p4] = acc;
}

// S1b: rcpS1[p] = 1 / sum_strips
__global__ __launch_bounds__(256) void k_s1b(const float4* __restrict__ part4,
                                             float4* __restrict__ rcp4) {
    const int i = blockIdx.x * 256 + threadIdx.x;    // [0, 16384)
    float4 a = {0.f, 0.f, 0.f, 0.f};
#pragma unroll
    for (int s = 0; s < NS2; ++s) {
        float4 v = part4[(size_t)s * (NPIX / 4) + i];
        a.x += v.x; a.y += v.y; a.z += v.z; a.w += v.w;
    }
    rcp4[i] = float4{1.0f / a.x, 1.0f / a.y, 1.0f / a.z, 1.0f / a.w};
}

// ---------------------------------------------------------------------------
// k_part: R14 structure (stagger + XCD swizzle + chunk-carry + snapshot +
// LDS rowsum — the only configuration that ever won), with two occupancy/
// latency knobs:
//   - NTHR=512 (8 waves): 4 blocks/CU x 8 = 32 waves/CU (full), stage wider.
//   - rowsum: ONE row per HALF-wave (8 waves x 2 halves = 16 rows in a
//     single round): 12 stride-32 LDS reads (2-way bank alias = free) +
//     5 intra-32 shuffles. Critical path ~270 cyc vs ~825 (3 sequential
//     rows/wave at 6 waves). Rowsum stays in LDS: 5 failed variants
//     (R10/R11/R13/R15/R16) proved it is latency-bound and belongs there.
// ---------------------------------------------------------------------------
__global__ __launch_bounds__(NTHR) void k_part(const float* __restrict__ ker,
                                               const float* __restrict__ rcpS1,
                                               const float* __restrict__ in2,
                                               float2* __restrict__ partial) {
    // generation stagger (no effect on results, only phase timing)
    switch (blockIdx.x >> 8) {
        case 1: __builtin_amdgcn_s_sleep(10); break;
        case 2: __builtin_amdgcn_s_sleep(20); break;
        case 3: __builtin_amdgcn_s_sleep(30); break;
        default: break;
    }

    __shared__ float tile[QB * KK];      // 23,104 B
    __shared__ float dt[LSZ * DTC];      // 6,232 B
    __shared__ float rcpS2s[QB];
    const int tid = threadIdx.x;
    const int lb  = ((blockIdx.x & 7) << 7) | (blockIdx.x >> 3);  // 1024 = 8*128
    const int q0  = lb * CHUNK;

    // stage reflected in2 patch (consumed after the k=0 stage barrier)
    {
        const int y0 = q0 >> 8, x0 = q0 & 255;
        for (int i = tid; i < LSZ * DTC; i += NTHR) {
            int ai = i / DTC, ci = i - ai * DTC;
            dt[i] = in2[refl(y0 + ai) * HWD + refl(x0 + ci)];
        }
    }

    // per-lane chunk-carry state
    const int t  = tid;
    const int j0 = t * NPIX + q0;             // < 2^25 for t<512
    const int r0 = j0 / KK;
    const int jm = j0 - r0 * KK;
    const int d0 = (jm == 0) ? CHUNK : (KK - jm);
    const int split = d0 < CHUNK ? d0 : CHUNK;     // [1, 64]
    const int la = t / LSZ, lb2 = t - LSZ * la;
    const int dbase = la * DTC + lb2;
    float ad = 0.f, as = 0.f, sd = 0.f, ss = 0.f;
    const int wave = tid >> 6, lane = tid & 63;
    const int half = lane >> 5, l32 = lane & 31;

    for (int k = 0; k < CT; ++k) {
        __syncthreads();   // previous sub-tile fully consumed (and dt, k=0)
        // stage ker sub-tile k (coalesced float4), scaled by rcpS1
        const int basek = (q0 + k * QB) * KK;            // %4 == 0
        const float4* k4 = (const float4*)(ker + basek);
        for (int i = tid; i < (QB * KK) / 4; i += NTHR) {
            float4 v = k4[i];
            int m = basek + i * 4;
            const float4 s = *(const float4*)(rcpS1 + (m & (NPIX - 1)));
            v.x *= s.x; v.y *= s.y; v.z *= s.z; v.w *= s.w;
            *(float4*)(tile + i * 4) = v;
        }
        __syncthreads();
        // per-q row sums -> rcpS2s: one row per half-wave, single round.
        {
            const int row = 2 * wave + half;             // 0..15, all threads
            float acc = 0.f;
            for (int e = l32; e < KK; e += 32) acc += tile[row * KK + e];
            acc += __shfl_xor(acc, 1);
            acc += __shfl_xor(acc, 2);
            acc += __shfl_xor(acc, 4);
            acc += __shfl_xor(acc, 8);
            acc += __shfl_xor(acc, 16);
            if (l32 == 0) rcpS2s[row] = 1.0f / acc;
        }
        __syncthreads();
        if (t < KK) {
#pragma unroll
            for (int o = 0; o < QB; ++o) {
                const int off = k * QB + o;
                if (off == split) { sd = ad; ss = as; }  // snapshot at boundary
                float v = tile[o * KK + t] * rcpS2s[o];
                float d = dt[dbase + off];
                ad += d * v;
                as += v;
            }
        }
    }

    if (t < KK) {
        const int slot = lb & (NSLOT - 1);
        if (split == CHUNK) {
            partial[(size_t)r0 * NSLOT + slot] = float2{ad, as};
        } else {
            partial[(size_t)r0 * NSLOT + slot] = float2{sd, ss};
            partial[(size_t)(r0 + 1) * NSLOT + slot] = float2{ad - sd, as - ss};
        }
    }
}

// ---------------------------------------------------------------------------
// k_out2: sum the valid slot window for row r (no zero-init needed).
// Chunks touching row r: [qs>>6 .. ql>>6] (mod GPART), <= 7 wide;
// slots = chunk & 7, distinct. Whole window lives in ONE 64B line.
// ---------------------------------------------------------------------------
__global__ __launch_bounds__(256) void k_out2(const float2* __restrict__ partial,
                                              float* __restrict__ out) {
    const int r = blockIdx.x * 256 + threadIdx.x;
    const int j0 = r * KK;
    const int qs = j0 & (NPIX - 1);
    const int ql = (j0 + KK - 1) & (NPIX - 1);
    const int first = qs >> 6;
    const int last  = ql >> 6;
    const int cnt = ((last - first) & (GPART - 1)) + 1;
    const float2* p = partial + (size_t)r * NSLOT;
    float dot = 0.f, sum = 0.f;
    for (int i = 0; i < cnt; ++i) {
        float2 v = p[(first + i) & (NSLOT - 1)];
        dot += v.x; sum += v.y;
    }
    out[r] = dot / sum;
}

// ---------------------------------------------------------------------------
// Minimal fallback path (tiny ws): direct strided gathers.
// ---------------------------------------------------------------------------
__global__ __launch_bounds__(256) void k_s1(const float* __restrict__ ker,
                                            float* __restrict__ rcpS1) {
    int p = blockIdx.x * blockDim.x + threadIdx.x;
    const float* kp = ker + p;
    float a = 0.f;
    for (int s = 0; s < KK; ++s) a += kp[(size_t)s * NPIX];
    rcpS1[p] = 1.0f / a;
}

__global__ __launch_bounds__(256) void k_s2_fallback(const float* __restrict__ ker,
                                                     const float* __restrict__ rcpS1,
                                                     float* __restrict__ rcpS2) {
    int lane = threadIdx.x & 63;
    int q = blockIdx.x * 4 + (threadIdx.x >> 6);
    int base = q * KK;
    float acc = 0.f;
    for (int t = lane; t < KK; t += 64)
        acc += ker[base + t] * rcpS1[(base + t) & (NPIX - 1)];
    for (int m = 1; m < 64; m <<= 1) acc += __shfl_xor(acc, m);
    if (lane == 0) rcpS2[q] = 1.0f / acc;
}

__global__ __launch_bounds__(256) void k_out_fallback(const float* __restrict__ ker,
                                                      const float* __restrict__ rcpS1,
                                                      const float* __restrict__ rcpS2,
                                                      const float* __restrict__ in2,
                                                      float* __restrict__ out) {
    int lane = threadIdx.x & 63;
    int r = blockIdx.x * 4 + (threadIdx.x >> 6);
    float vsum = 0.f, vdot = 0.f;
    for (int u = lane; u < KK; u += 64) {
        int jj = r * KK + u;
        int t  = jj >> 16;
        int q  = jj & (NPIX - 1);
        int m  = q * KK + t;
        float v = ker[m] * rcpS1[m & (NPIX - 1)] * rcpS2[q];
        int y = q >> 8, x = q & 255;
        int a = t / LSZ, b = t - a * LSZ;
        float d = in2[refl(y + a) * HWD + refl(x + b)];
        vsum += v;
        vdot += d * v;
    }
    for (int mm = 1; mm < 64; mm <<= 1) {
        vsum += __shfl_xor(vsum, mm);
        vdot += __shfl_xor(vdot, mm);
    }
    if (lane == 0) out[r] = vdot / vsum;
}

extern "C" void kernel_launch(void* const* d_in, const int* in_sizes, int n_in,
                              void* d_out, int out_size, void* d_ws, size_t ws_size,
                              hipStream_t stream) {
    const float* inp = (const float*)d_in[0];   // (1,3,256,256)
    const float* ker = (const float*)d_in[1];   // (19,19,256,256)
    float* out = (float*)d_out;                 // (1,1,256,256)
    const float* in2 = inp + 2 * NPIX;          // channel 2

    float*  rcpS1   = (float*)d_ws;                           // NPIX
    float*  s1part  = rcpS1 + NPIX;                           // NS2*NPIX
    float2* partial = (float2*)(s1part + (size_t)NS2 * NPIX); // NPIX*NSLOT float2

    const size_t needed = ((size_t)NPIX * (1 + NS2) +
                           (size_t)NPIX * NSLOT * 2) * sizeof(float);  // ~8.25 MB

    if (ws_size >= needed) {
        dim3 g1(NPIX / 4 / 256, NS2);   // (64, 16)
        k_s1a<<<g1, 256, 0, stream>>>((const float4*)ker, (float4*)s1part);
        k_s1b<<<NPIX / 4 / 256, 256, 0, stream>>>((const float4*)s1part, (float4*)rcpS1);
        k_part<<<GPART, NTHR, 0, stream>>>(ker, rcpS1, in2, partial);
        k_out2<<<NPIX / 256, 256, 0, stream>>>(partial, out);
    } else {
        float* rcpS2 = rcpS1 + NPIX;   // fallback needs only 512 KB
        k_s1<<<NPIX / 256, 256, 0, stream>>>(ker, rcpS1);
        k_s2_fallback<<<NPIX / 4, 256, 0, stream>>>(ker, rcpS1, rcpS2);
        k_out_fallback<<<NPIX / 4, 256, 0, stream>>>(ker, rcpS1, rcpS2, in2, out);
    }
}